// Round 22
// baseline (135.589 us; speedup 1.0000x reference)
//
#include <hip/hip_runtime.h>

#define LOG2E 1.44269504088896340736f

typedef _Float16 f16_t;
typedef f16_t f16x2 __attribute__((ext_vector_type(2)));
typedef f16_t f16x4 __attribute__((ext_vector_type(4)));
typedef f16_t f16x8 __attribute__((ext_vector_type(8)));
typedef float f32x4 __attribute__((ext_vector_type(4)));

// Problem constants: N=4096 nodes, F_in=512, F_out=128, H=8 heads.

// ---- K0: cvt (x->f16, W transpose->f16) ----
__global__ __launch_bounds__(256) void k_cvt(const float* __restrict__ x,
                                             f16_t* __restrict__ xh,
                                             const float* __restrict__ W,
                                             f16_t* __restrict__ WT) {
  const int bx = blockIdx.x;
  if (bx < 1024) {  // x fp32 -> fp16
    const int t = bx * 256 + threadIdx.x;
    const f32x4 a = ((const f32x4*)x)[t * 2];
    const f32x4 b = ((const f32x4*)x)[t * 2 + 1];
    f16x8 o;
#pragma unroll
    for (int i = 0; i < 4; ++i) { o[i] = (f16_t)a[i]; o[i + 4] = (f16_t)b[i]; }
    ((f16x8*)xh)[t] = o;
  } else {  // W [h][k][o] -> WT [h][o][k] fp16
    const int t = (bx - 1024) * 256 + threadIdx.x;
    const int k = t & 511, o = (t >> 9) & 127, h = t >> 16;
    WT[t] = (f16_t)W[((h << 9) + k) * 128 + o];
  }
}

// ---- K1: FUSED adjacency pack + Wh-GEMM ----
// Blocks 0..8191: pack adj (64MB) -> bitmask (2MB) -- dispatched FIRST so
// the HBM stream saturates from t=0; the 512 GEMM blocks (8192..8703)
// enter as pack blocks retire and overlap the pack tail. Mask isn't
// consumed until k_pv. GEMM: 64 rows x 128 cols per block (R18-verified),
// staged-f16 x, WhB pre-swizzled store, piecewise-exp tables epilogue.
__global__ __launch_bounds__(256) void k_gemm_pack(const f16_t* __restrict__ xh,
                                                   const f16_t* __restrict__ WT,
                                                   const float* __restrict__ a_src,
                                                   const float* __restrict__ a_dst,
                                                   f16_t* __restrict__ WhB,
                                                   f16_t* __restrict__ EA,
                                                   f16_t* __restrict__ EA2,
                                                   f16_t* __restrict__ EB,
                                                   f16_t* __restrict__ EB2,
                                                   const int* __restrict__ adj,
                                                   unsigned char* __restrict__ mask8) {
  const int bx = blockIdx.x;
  if (bx < 8192) {  // ---- adjacency pack ----
    const int t = bx * 256 + threadIdx.x;
    const int4 a = ((const int4*)adj)[t * 2];
    const int4 b = ((const int4*)adj)[t * 2 + 1];
    unsigned v = (a.x > 0) | ((a.y > 0) << 1) | ((a.z > 0) << 2) | ((a.w > 0) << 3) |
                 ((b.x > 0) << 4) | ((b.y > 0) << 5) | ((b.z > 0) << 6) | ((b.w > 0) << 7);
    mask8[t] = (unsigned char)v;
    return;
  }
  // ---- Wh GEMM (h-first flatten for XCD spread) ----
  const int gb = bx - 8192;
  const int h = gb & 7;
  const int n0 = (gb >> 3) * 64;
  const int lane = threadIdx.x & 63;
  const int w = threadIdx.x >> 6;
  const int col = lane & 15;
  const int kg = lane >> 4;
  const f16_t* xrow = xh + (size_t)(n0 + w * 16 + col) * 512 + kg * 8;
  const f16_t* wb = WT + ((size_t)h << 16) + (size_t)col * 512 + kg * 8;
  f32x4 acc[8] = {};
  for (int kk = 0; kk < 512; kk += 32) {
    const f16x8 a = *(const f16x8*)(xrow + kk);
#pragma unroll
    for (int ot = 0; ot < 8; ++ot) {
      const f16x8 b = *(const f16x8*)(wb + ot * (16 * 512) + kk);
      acc[ot] = __builtin_amdgcn_mfma_f32_16x16x32_f16(a, b, acc[ot], 0, 0, 0);
    }
  }
  float ps[4] = {0.f, 0.f, 0.f, 0.f}, pd[4] = {0.f, 0.f, 0.f, 0.f};
#pragma unroll
  for (int ot = 0; ot < 8; ++ot) {
    const float as = a_src[h * 128 + ot * 16 + col];
    const float ad = a_dst[h * 128 + ot * 16 + col];
#pragma unroll
    for (int r = 0; r < 4; ++r) { ps[r] += acc[ot][r] * as; pd[r] += acc[ot][r] * ad; }
  }
#pragma unroll
  for (int m = 1; m < 16; m <<= 1) {
#pragma unroll
    for (int r = 0; r < 4; ++r) {
      ps[r] += __shfl_xor(ps[r], m, 64);
      pd[r] += __shfl_xor(pd[r], m, 64);
    }
  }
  const int nb = n0 + w * 16 + kg * 4;  // node index of acc[.][0]
  if (col == 0) {
#pragma unroll
    for (int r = 0; r < 4; ++r) {
      const float fs = ps[r] * LOG2E;
      const float fd = pd[r] * LOG2E;
      const int idx = h * 4096 + nb + r;
      EA[idx] = (f16_t)__builtin_amdgcn_exp2f(fs);
      EA2[idx] = (f16_t)__builtin_amdgcn_exp2f(0.2f * fs);
      EB[idx] = (f16_t)__builtin_amdgcn_exp2f(fd);
      EB2[idx] = (f16_t)__builtin_amdgcn_exp2f(0.2f * fd);
    }
  }
  // swizzled store: (h,o,j) -> WhB[((h*128+j/32)*8+o/16)*512 + ((j>>3)&3)*128 + (o&15)*8 + (j&7)]
  const int jb = nb >> 5;
  const int kgt = (nb >> 3) & 3;
  const int e0 = nb & 4;
  const size_t base = ((size_t)(h * 128 + jb) * 8) * 512 + kgt * 128 + col * 8 + e0;
#pragma unroll
  for (int ot = 0; ot < 8; ++ot) {
    f16x4 v;
#pragma unroll
    for (int r = 0; r < 4; ++r) v[r] = (f16_t)acc[ot][r];
    *(f16x4*)(WhB + base + ot * 512) = v;
  }
}

// P-generation: p = max(EA_i*EB_j, EA2_i*EB2_j) * m_ij (piecewise exp of
// LeakyReLU), packed fp16, mask via 16-entry nibble LUTs.
#define GEN_P(dst, mw, vb, vb2)                                                            \
  {                                                                                        \
    const unsigned bb_ = (mw) & 255u;                                                      \
    const f16x4 lmL_ = *(const f16x4*)(&lut4[bb_ & 15u][0]);                               \
    const f16x4 lmH_ = *(const f16x4*)(&lut4[bb_ >> 4][0]);                                \
    const f16x2* vp_ = (const f16x2*)&(vb);                                                \
    const f16x2* v2p_ = (const f16x2*)&(vb2);                                              \
    ((f16x2*)&(dst))[0] = __builtin_elementwise_max(As * vp_[0], A2s * v2p_[0]) * ((const f16x2*)&lmL_)[0]; \
    ((f16x2*)&(dst))[1] = __builtin_elementwise_max(As * vp_[1], A2s * v2p_[1]) * ((const f16x2*)&lmL_)[1]; \
    ((f16x2*)&(dst))[2] = __builtin_elementwise_max(As * vp_[2], A2s * v2p_[2]) * ((const f16x2*)&lmH_)[0]; \
    ((f16x2*)&(dst))[3] = __builtin_elementwise_max(As * vp_[3], A2s * v2p_[3]) * ((const f16x2*)&lmH_)[1]; \
  }

// ---- K2: masked softmax + PV, fused merge (design F-pipelined, 8 waves) ----
// R18's verified structure (58.9us). Block = 512 thr = 2 quads x 4 waves.
// Quad wq owns j-slice [wq*2048, +2048); within a quad, wave w gens P for
// row-group w (1x VALU), exchanges via quad-private dbuf LDS, MFMAs all 4
// frags against its o-quarter (2 B-frags). Pipelined round: read P(it) ->
// MFMA(it) -> gen P(it+1) -> write -> barrier. den via ones-B MFMA.
// Epilogue: quad 1 dumps acc into retired lds_P; quad 0 merges + writes out.
// grid = 64 i-tiles x 8 heads = 512 blocks = 2/CU.
__global__ __launch_bounds__(512, 4) void k_pv(const f16_t* __restrict__ WhB,
                                               const f16_t* __restrict__ EA,
                                               const f16_t* __restrict__ EA2,
                                               const f16_t* __restrict__ EB,
                                               const f16_t* __restrict__ EB2,
                                               const unsigned char* __restrict__ mask,
                                               float* __restrict__ out) {
  __shared__ __align__(16) unsigned char lds_mask[64 * 528];       // 33.8 KB
  __shared__ __align__(16) unsigned short lut4[16][4];
  __shared__ __align__(16) f16_t lds_P[2][2][4][512];              // 16 KB; reused as merge buf
  __shared__ float lds_den[2][64];
  const int bx = blockIdx.x;
  const int h = bx & 7;            // head -> XCD round-robin
  const int i0 = (bx >> 3) * 64;   // 64-row i-tile
  const int tid = threadIdx.x;
  // stage mask tile: 64 rows x 512B (pitch 528), one-time coalesced copy
  {
    if (tid < 16) {
#pragma unroll
      for (int e = 0; e < 4; ++e) lut4[tid][e] = ((tid >> e) & 1) ? 0x3C00 : 0;
    }
    const int row = tid >> 3, ch = (tid & 7) * 64;
    const uint4* src = (const uint4*)(mask + (size_t)(i0 + row) * 512 + ch);
    uint4* dst = (uint4*)(lds_mask + row * 528 + ch);
#pragma unroll
    for (int i = 0; i < 4; ++i) dst[i] = src[i];
  }
  __syncthreads();
  const int wq = tid >> 8;         // j-slice quad (0..1)
  const int w = (tid >> 6) & 3;    // row-group owner (P-gen) AND o-quarter
  const int lane = tid & 63;
  const int col = lane & 15, kg = lane >> 4;
  const int sh = kg * 8;
  const int jbeg = wq * 2048;
  f16x2 As, A2s;
  {
    const f16_t a = EA[h * 4096 + i0 + w * 16 + col];
    const f16_t a2 = EA2[h * 4096 + i0 + w * 16 + col];
    As = (f16x2){a, a};
    A2s = (f16x2){a2, a2};
  }
  f16x8 ones8;
#pragma unroll
  for (int e = 0; e < 8; ++e) ones8[e] = (f16_t)1.0f;
  const unsigned char* mrow = lds_mask + (w * 16 + col) * 528 + wq * 256;
  const f16_t* EBp = EB + h * 4096 + jbeg + kg * 8;
  const f16_t* EB2p = EB2 + h * 4096 + jbeg + kg * 8;
  const f16_t* whB = WhB + ((size_t)h << 19) + (size_t)(jbeg >> 5) * 4096 + (2 * w) * 512 + lane * 8;
  f32x4 acc[4][2] = {};
  f32x4 den_acc = {};
  // ---- prologue: gen P(0), write, barrier; stage B(0), EB(1) ----
  uint4 mdc = *(const uint4*)(mrow);  // mask words for rounds 0..3
  f16x8 cb0 = *(const f16x8*)(whB);
  f16x8 cb1 = *(const f16x8*)(whB + 512);
  f16x8 evb = *(const f16x8*)(EBp + 32);
  f16x8 evb2 = *(const f16x8*)(EB2p + 32);
  {
    const f16x8 gvb = *(const f16x8*)(EBp);
    const f16x8 gvb2 = *(const f16x8*)(EB2p);
    f16x8 a0;
    GEN_P(a0, mdc.x >> sh, gvb, gvb2);
    den_acc = __builtin_amdgcn_mfma_f32_16x16x32_f16(a0, ones8, den_acc, 0, 0, 0);
    *(f16x8*)(&lds_P[wq][0][w][lane * 8]) = a0;
  }
  __syncthreads();
  f16x8 aCur;
  for (int it4 = 0; it4 < 16; ++it4) {
    const uint4 mdn = *(const uint4*)(mrow + ((it4 + 1) & 15) * 16);
#pragma unroll
    for (int q = 0; q < 4; ++q) {
      const int it = it4 * 4 + q;
      const int buf = q & 1;  // == it&1
      // 1. read all 4 P(it) fragments (previous round's writes, barrier'd)
      const f16x8 p0 = *(const f16x8*)(&lds_P[wq][buf][0][lane * 8]);
      const f16x8 p1 = *(const f16x8*)(&lds_P[wq][buf][1][lane * 8]);
      const f16x8 p2 = *(const f16x8*)(&lds_P[wq][buf][2][lane * 8]);
      const f16x8 p3 = *(const f16x8*)(&lds_P[wq][buf][3][lane * 8]);
      // 2. prefetch B(it+1)
      const f16_t* wpn = whB + (size_t)(it + 1) * 4096;  // last-iter overrun harmless
      const f16x8 nb0 = *(const f16x8*)(wpn);
      const f16x8 nb1 = *(const f16x8*)(wpn + 512);
      // 3. MFMA(it) — issue first so gen-VALU streams under the MFMA pipe
      acc[0][0] = __builtin_amdgcn_mfma_f32_16x16x32_f16(p0, cb0, acc[0][0], 0, 0, 0);
      acc[0][1] = __builtin_amdgcn_mfma_f32_16x16x32_f16(p0, cb1, acc[0][1], 0, 0, 0);
      acc[1][0] = __builtin_amdgcn_mfma_f32_16x16x32_f16(p1, cb0, acc[1][0], 0, 0, 0);
      acc[1][1] = __builtin_amdgcn_mfma_f32_16x16x32_f16(p1, cb1, acc[1][1], 0, 0, 0);
      acc[2][0] = __builtin_amdgcn_mfma_f32_16x16x32_f16(p2, cb0, acc[2][0], 0, 0, 0);
      acc[2][1] = __builtin_amdgcn_mfma_f32_16x16x32_f16(p2, cb1, acc[2][1], 0, 0, 0);
      acc[3][0] = __builtin_amdgcn_mfma_f32_16x16x32_f16(p3, cb0, acc[3][0], 0, 0, 0);
      acc[3][1] = __builtin_amdgcn_mfma_f32_16x16x32_f16(p3, cb1, acc[3][1], 0, 0, 0);
      // 4. gen P(it+1)
      const unsigned mw = ((q == 0) ? mdc.y : (q == 1) ? mdc.z : (q == 2) ? mdc.w : mdn.x) >> sh;
      GEN_P(aCur, mw, evb, evb2);
      // 5. write P(it+1) early, then den-MFMA (round-64 gen is a discard)
      *(f16x8*)(&lds_P[wq][buf ^ 1][w][lane * 8]) = aCur;
      if (q < 3 || it4 < 15)
        den_acc = __builtin_amdgcn_mfma_f32_16x16x32_f16(aCur, ones8, den_acc, 0, 0, 0);
      // 6. prefetch EB(it+2) for the next gen
      const f16x8 nevb = *(const f16x8*)(EBp + (it + 2) * 32);
      const f16x8 nevb2 = *(const f16x8*)(EB2p + (it + 2) * 32);
      __syncthreads();
      cb0 = nb0; cb1 = nb1; evb = nevb; evb2 = nevb2;
    }
    mdc = mdn;
  }
  // den: D-row = A-row -> lane holds rowsum of rows w*16 + kg*4 + r (any col)
  if (col == 0) {
#pragma unroll
    for (int r = 0; r < 4; ++r) lds_den[wq][w * 16 + kg * 4 + r] = den_acc[r];
  }
  // quad 1 dumps acc (f16) into retired lds_P region as [64][128]
  f16_t* mbuf = (f16_t*)lds_P;
  if (wq == 1) {
#pragma unroll
    for (int g = 0; g < 4; ++g) {
#pragma unroll
      for (int t = 0; t < 2; ++t) {
#pragma unroll
        for (int r = 0; r < 4; ++r) {
          mbuf[(g * 16 + kg * 4 + r) * 128 + w * 32 + t * 16 + col] = (f16_t)acc[g][t][r];
        }
      }
    }
  }
  __syncthreads();
  // quad 0: merge + normalize + write out[n][h*128+o]
  if (wq == 0) {
#pragma unroll
    for (int g = 0; g < 4; ++g) {
#pragma unroll
      for (int r = 0; r < 4; ++r) {
        const int row = g * 16 + kg * 4 + r;
        const float inv = __builtin_amdgcn_rcpf(lds_den[0][row] + lds_den[1][row]);
        float* op = out + (size_t)(i0 + row) * 1024 + h * 128 + w * 32;
#pragma unroll
        for (int t = 0; t < 2; ++t) {
          const float v = acc[g][t][r] + (float)mbuf[row * 128 + w * 32 + t * 16 + col];
          op[t * 16 + col] = v * inv;
        }
      }
    }
  }
}

extern "C" void kernel_launch(void* const* d_in, const int* in_sizes, int n_in,
                              void* d_out, int out_size, void* d_ws, size_t ws_size,
                              hipStream_t stream) {
  const float* x = (const float*)d_in[0];
  const int* adj = (const int*)d_in[1];
  const float* W = (const float*)d_in[2];
  const float* a_src = (const float*)d_in[3];
  const float* a_dst = (const float*)d_in[4];
  float* out = (float*)d_out;
  char* ws = (char*)d_ws;
  // workspace layout (bytes):
  //   WhB   swizzled f16          : 0        .. 8388608
  //   xh    [4096][512] f16       : 8388608  .. 12582912
  //   WT    [8][128][512] f16     : 12582912 .. 13631488
  //   mask  [4096][512] u8        : 13631488 .. 15728640
  //   EA/EA2/EB/EB2 [8][4096] f16 : 15728640 .. 15990784 (4 x 64KB)
  f16_t* WhB = (f16_t*)(ws);
  f16_t* xh = (f16_t*)(ws + 8388608);
  f16_t* WT = (f16_t*)(ws + 12582912);
  unsigned char* mask8 = (unsigned char*)(ws + 13631488);
  f16_t* EA = (f16_t*)(ws + 15728640);
  f16_t* EA2 = (f16_t*)(ws + 15794176);
  f16_t* EB = (f16_t*)(ws + 15859712);
  f16_t* EB2 = (f16_t*)(ws + 15925248);

  k_cvt<<<3072, 256, 0, stream>>>(x, xh, W, WT);
  k_gemm_pack<<<8704, 256, 0, stream>>>(xh, WT, a_src, a_dst, WhB, EA, EA2, EB, EB2,
                                        adj, mask8);
  k_pv<<<512, 512, 0, stream>>>(WhB, EA, EA2, EB, EB2, mask8, out);
}

// Round 23
// 102.399 us; speedup vs baseline: 1.3241x; 1.3241x over previous
//
#include <hip/hip_runtime.h>

#define LOG2E 1.44269504088896340736f

typedef _Float16 f16_t;
typedef f16_t f16x2 __attribute__((ext_vector_type(2)));
typedef f16_t f16x4 __attribute__((ext_vector_type(4)));
typedef f16_t f16x8 __attribute__((ext_vector_type(8)));
typedef float f32x4 __attribute__((ext_vector_type(4)));

// Problem constants: N=4096 nodes, F_in=512, F_out=128, H=8 heads.

// ---- K0: cvt (x->f16, W transpose->f16) ----
__global__ __launch_bounds__(256) void k_cvt(const float* __restrict__ x,
                                             f16_t* __restrict__ xh,
                                             const float* __restrict__ W,
                                             f16_t* __restrict__ WT) {
  const int bx = blockIdx.x;
  if (bx < 1024) {  // x fp32 -> fp16
    const int t = bx * 256 + threadIdx.x;
    const f32x4 a = ((const f32x4*)x)[t * 2];
    const f32x4 b = ((const f32x4*)x)[t * 2 + 1];
    f16x8 o;
#pragma unroll
    for (int i = 0; i < 4; ++i) { o[i] = (f16_t)a[i]; o[i + 4] = (f16_t)b[i]; }
    ((f16x8*)xh)[t] = o;
  } else {  // W [h][k][o] -> WT [h][o][k] fp16
    const int t = (bx - 1024) * 256 + threadIdx.x;
    const int k = t & 511, o = (t >> 9) & 127, h = t >> 16;
    WT[t] = (f16_t)W[((h << 9) + k) * 128 + o];
  }
}

// ---- K1: FUSED Wh-GEMM + adjacency pack (R18 champion order) ----
// Blocks 0..511: Wh GEMM (long pole, launches at t=0). Blocks 512..8703:
// pack adj (64MB->2MB), HBM-bound, fills CUs AROUND the resident GEMM
// blocks. Mask isn't consumed until k_pv. Pack-first order (R22) serialized
// the GEMM behind the pack wave: -33us. Keep GEMM-first.
__global__ __launch_bounds__(256) void k_gemm_pack(const f16_t* __restrict__ xh,
                                                   const f16_t* __restrict__ WT,
                                                   const float* __restrict__ a_src,
                                                   const float* __restrict__ a_dst,
                                                   f16_t* __restrict__ WhB,
                                                   f16_t* __restrict__ EA,
                                                   f16_t* __restrict__ EA2,
                                                   f16_t* __restrict__ EB,
                                                   f16_t* __restrict__ EB2,
                                                   const int* __restrict__ adj,
                                                   unsigned char* __restrict__ mask8) {
  const int bx = blockIdx.x;
  if (bx >= 512) {  // ---- adjacency pack ----
    const int t = (bx - 512) * 256 + threadIdx.x;
    const int4 a = ((const int4*)adj)[t * 2];
    const int4 b = ((const int4*)adj)[t * 2 + 1];
    unsigned v = (a.x > 0) | ((a.y > 0) << 1) | ((a.z > 0) << 2) | ((a.w > 0) << 3) |
                 ((b.x > 0) << 4) | ((b.y > 0) << 5) | ((b.z > 0) << 6) | ((b.w > 0) << 7);
    mask8[t] = (unsigned char)v;
    return;
  }
  // ---- Wh GEMM (h-first flatten for XCD spread) ----
  const int h = bx & 7;
  const int n0 = (bx >> 3) * 64;
  const int lane = threadIdx.x & 63;
  const int w = threadIdx.x >> 6;
  const int col = lane & 15;
  const int kg = lane >> 4;
  const f16_t* xrow = xh + (size_t)(n0 + w * 16 + col) * 512 + kg * 8;
  const f16_t* wb = WT + ((size_t)h << 16) + (size_t)col * 512 + kg * 8;
  f32x4 acc[8] = {};
  for (int kk = 0; kk < 512; kk += 32) {
    const f16x8 a = *(const f16x8*)(xrow + kk);
#pragma unroll
    for (int ot = 0; ot < 8; ++ot) {
      const f16x8 b = *(const f16x8*)(wb + ot * (16 * 512) + kk);
      acc[ot] = __builtin_amdgcn_mfma_f32_16x16x32_f16(a, b, acc[ot], 0, 0, 0);
    }
  }
  float ps[4] = {0.f, 0.f, 0.f, 0.f}, pd[4] = {0.f, 0.f, 0.f, 0.f};
#pragma unroll
  for (int ot = 0; ot < 8; ++ot) {
    const float as = a_src[h * 128 + ot * 16 + col];
    const float ad = a_dst[h * 128 + ot * 16 + col];
#pragma unroll
    for (int r = 0; r < 4; ++r) { ps[r] += acc[ot][r] * as; pd[r] += acc[ot][r] * ad; }
  }
#pragma unroll
  for (int m = 1; m < 16; m <<= 1) {
#pragma unroll
    for (int r = 0; r < 4; ++r) {
      ps[r] += __shfl_xor(ps[r], m, 64);
      pd[r] += __shfl_xor(pd[r], m, 64);
    }
  }
  const int nb = n0 + w * 16 + kg * 4;  // node index of acc[.][0]
  if (col == 0) {
#pragma unroll
    for (int r = 0; r < 4; ++r) {
      const float fs = ps[r] * LOG2E;
      const float fd = pd[r] * LOG2E;
      const int idx = h * 4096 + nb + r;
      EA[idx] = (f16_t)__builtin_amdgcn_exp2f(fs);
      EA2[idx] = (f16_t)__builtin_amdgcn_exp2f(0.2f * fs);
      EB[idx] = (f16_t)__builtin_amdgcn_exp2f(fd);
      EB2[idx] = (f16_t)__builtin_amdgcn_exp2f(0.2f * fd);
    }
  }
  // swizzled store: (h,o,j) -> WhB[((h*128+j/32)*8+o/16)*512 + ((j>>3)&3)*128 + (o&15)*8 + (j&7)]
  const int jb = nb >> 5;
  const int kgt = (nb >> 3) & 3;
  const int e0 = nb & 4;
  const size_t base = ((size_t)(h * 128 + jb) * 8) * 512 + kgt * 128 + col * 8 + e0;
#pragma unroll
  for (int ot = 0; ot < 8; ++ot) {
    f16x4 v;
#pragma unroll
    for (int r = 0; r < 4; ++r) v[r] = (f16_t)acc[ot][r];
    *(f16x4*)(WhB + base + ot * 512) = v;
  }
}

// P-generation: p = max(EA_i*EB_j, EA2_i*EB2_j) * m_ij (piecewise exp of
// LeakyReLU), packed fp16, mask via 16-entry nibble LUTs.
#define GEN_P(dst, mw, vb, vb2)                                                            \
  {                                                                                        \
    const unsigned bb_ = (mw) & 255u;                                                      \
    const f16x4 lmL_ = *(const f16x4*)(&lut4[bb_ & 15u][0]);                               \
    const f16x4 lmH_ = *(const f16x4*)(&lut4[bb_ >> 4][0]);                                \
    const f16x2* vp_ = (const f16x2*)&(vb);                                                \
    const f16x2* v2p_ = (const f16x2*)&(vb2);                                              \
    ((f16x2*)&(dst))[0] = __builtin_elementwise_max(As * vp_[0], A2s * v2p_[0]) * ((const f16x2*)&lmL_)[0]; \
    ((f16x2*)&(dst))[1] = __builtin_elementwise_max(As * vp_[1], A2s * v2p_[1]) * ((const f16x2*)&lmL_)[1]; \
    ((f16x2*)&(dst))[2] = __builtin_elementwise_max(As * vp_[2], A2s * v2p_[2]) * ((const f16x2*)&lmH_)[0]; \
    ((f16x2*)&(dst))[3] = __builtin_elementwise_max(As * vp_[3], A2s * v2p_[3]) * ((const f16x2*)&lmH_)[1]; \
  }

// ---- K2: masked softmax + PV, fused merge (design F-pipelined, 8 waves) ----
// R18's verified structure (58.9us). Block = 512 thr = 2 quads x 4 waves.
// Quad wq owns j-slice [wq*2048, +2048); within a quad, wave w gens P for
// row-group w (1x VALU), exchanges via quad-private dbuf LDS, MFMAs all 4
// frags against its o-quarter (2 B-frags). Pipelined round: read P(it) ->
// MFMA(it) -> gen P(it+1) -> write -> barrier. den via ones-B MFMA.
// Epilogue: quad 1 dumps acc into retired lds_P; quad 0 merges + writes out.
// grid = 64 i-tiles x 8 heads = 512 blocks = 2/CU.
__global__ __launch_bounds__(512, 4) void k_pv(const f16_t* __restrict__ WhB,
                                               const f16_t* __restrict__ EA,
                                               const f16_t* __restrict__ EA2,
                                               const f16_t* __restrict__ EB,
                                               const f16_t* __restrict__ EB2,
                                               const unsigned char* __restrict__ mask,
                                               float* __restrict__ out) {
  __shared__ __align__(16) unsigned char lds_mask[64 * 528];       // 33.8 KB
  __shared__ __align__(16) unsigned short lut4[16][4];
  __shared__ __align__(16) f16_t lds_P[2][2][4][512];              // 16 KB; reused as merge buf
  __shared__ float lds_den[2][64];
  const int bx = blockIdx.x;
  const int h = bx & 7;            // head -> XCD round-robin
  const int i0 = (bx >> 3) * 64;   // 64-row i-tile
  const int tid = threadIdx.x;
  // stage mask tile: 64 rows x 512B (pitch 528), one-time coalesced copy
  {
    if (tid < 16) {
#pragma unroll
      for (int e = 0; e < 4; ++e) lut4[tid][e] = ((tid >> e) & 1) ? 0x3C00 : 0;
    }
    const int row = tid >> 3, ch = (tid & 7) * 64;
    const uint4* src = (const uint4*)(mask + (size_t)(i0 + row) * 512 + ch);
    uint4* dst = (uint4*)(lds_mask + row * 528 + ch);
#pragma unroll
    for (int i = 0; i < 4; ++i) dst[i] = src[i];
  }
  __syncthreads();
  const int wq = tid >> 8;         // j-slice quad (0..1)
  const int w = (tid >> 6) & 3;    // row-group owner (P-gen) AND o-quarter
  const int lane = tid & 63;
  const int col = lane & 15, kg = lane >> 4;
  const int sh = kg * 8;
  const int jbeg = wq * 2048;
  f16x2 As, A2s;
  {
    const f16_t a = EA[h * 4096 + i0 + w * 16 + col];
    const f16_t a2 = EA2[h * 4096 + i0 + w * 16 + col];
    As = (f16x2){a, a};
    A2s = (f16x2){a2, a2};
  }
  f16x8 ones8;
#pragma unroll
  for (int e = 0; e < 8; ++e) ones8[e] = (f16_t)1.0f;
  const unsigned char* mrow = lds_mask + (w * 16 + col) * 528 + wq * 256;
  const f16_t* EBp = EB + h * 4096 + jbeg + kg * 8;
  const f16_t* EB2p = EB2 + h * 4096 + jbeg + kg * 8;
  const f16_t* whB = WhB + ((size_t)h << 19) + (size_t)(jbeg >> 5) * 4096 + (2 * w) * 512 + lane * 8;
  f32x4 acc[4][2] = {};
  f32x4 den_acc = {};
  // ---- prologue: gen P(0), write, barrier; stage B(0), EB(1) ----
  uint4 mdc = *(const uint4*)(mrow);  // mask words for rounds 0..3
  f16x8 cb0 = *(const f16x8*)(whB);
  f16x8 cb1 = *(const f16x8*)(whB + 512);
  f16x8 evb = *(const f16x8*)(EBp + 32);
  f16x8 evb2 = *(const f16x8*)(EB2p + 32);
  {
    const f16x8 gvb = *(const f16x8*)(EBp);
    const f16x8 gvb2 = *(const f16x8*)(EB2p);
    f16x8 a0;
    GEN_P(a0, mdc.x >> sh, gvb, gvb2);
    den_acc = __builtin_amdgcn_mfma_f32_16x16x32_f16(a0, ones8, den_acc, 0, 0, 0);
    *(f16x8*)(&lds_P[wq][0][w][lane * 8]) = a0;
  }
  __syncthreads();
  f16x8 aCur;
  for (int it4 = 0; it4 < 16; ++it4) {
    const uint4 mdn = *(const uint4*)(mrow + ((it4 + 1) & 15) * 16);
#pragma unroll
    for (int q = 0; q < 4; ++q) {
      const int it = it4 * 4 + q;
      const int buf = q & 1;  // == it&1
      // 1. read all 4 P(it) fragments (previous round's writes, barrier'd)
      const f16x8 p0 = *(const f16x8*)(&lds_P[wq][buf][0][lane * 8]);
      const f16x8 p1 = *(const f16x8*)(&lds_P[wq][buf][1][lane * 8]);
      const f16x8 p2 = *(const f16x8*)(&lds_P[wq][buf][2][lane * 8]);
      const f16x8 p3 = *(const f16x8*)(&lds_P[wq][buf][3][lane * 8]);
      // 2. prefetch B(it+1)
      const f16_t* wpn = whB + (size_t)(it + 1) * 4096;  // last-iter overrun harmless
      const f16x8 nb0 = *(const f16x8*)(wpn);
      const f16x8 nb1 = *(const f16x8*)(wpn + 512);
      // 3. MFMA(it) — issue first so gen-VALU streams under the MFMA pipe
      acc[0][0] = __builtin_amdgcn_mfma_f32_16x16x32_f16(p0, cb0, acc[0][0], 0, 0, 0);
      acc[0][1] = __builtin_amdgcn_mfma_f32_16x16x32_f16(p0, cb1, acc[0][1], 0, 0, 0);
      acc[1][0] = __builtin_amdgcn_mfma_f32_16x16x32_f16(p1, cb0, acc[1][0], 0, 0, 0);
      acc[1][1] = __builtin_amdgcn_mfma_f32_16x16x32_f16(p1, cb1, acc[1][1], 0, 0, 0);
      acc[2][0] = __builtin_amdgcn_mfma_f32_16x16x32_f16(p2, cb0, acc[2][0], 0, 0, 0);
      acc[2][1] = __builtin_amdgcn_mfma_f32_16x16x32_f16(p2, cb1, acc[2][1], 0, 0, 0);
      acc[3][0] = __builtin_amdgcn_mfma_f32_16x16x32_f16(p3, cb0, acc[3][0], 0, 0, 0);
      acc[3][1] = __builtin_amdgcn_mfma_f32_16x16x32_f16(p3, cb1, acc[3][1], 0, 0, 0);
      // 4. gen P(it+1)
      const unsigned mw = ((q == 0) ? mdc.y : (q == 1) ? mdc.z : (q == 2) ? mdc.w : mdn.x) >> sh;
      GEN_P(aCur, mw, evb, evb2);
      // 5. write P(it+1) early, then den-MFMA (round-64 gen is a discard)
      *(f16x8*)(&lds_P[wq][buf ^ 1][w][lane * 8]) = aCur;
      if (q < 3 || it4 < 15)
        den_acc = __builtin_amdgcn_mfma_f32_16x16x32_f16(aCur, ones8, den_acc, 0, 0, 0);
      // 6. prefetch EB(it+2) for the next gen
      const f16x8 nevb = *(const f16x8*)(EBp + (it + 2) * 32);
      const f16x8 nevb2 = *(const f16x8*)(EB2p + (it + 2) * 32);
      __syncthreads();
      cb0 = nb0; cb1 = nb1; evb = nevb; evb2 = nevb2;
    }
    mdc = mdn;
  }
  // den: D-row = A-row -> lane holds rowsum of rows w*16 + kg*4 + r (any col)
  if (col == 0) {
#pragma unroll
    for (int r = 0; r < 4; ++r) lds_den[wq][w * 16 + kg * 4 + r] = den_acc[r];
  }
  // quad 1 dumps acc (f16) into retired lds_P region as [64][128]
  f16_t* mbuf = (f16_t*)lds_P;
  if (wq == 1) {
#pragma unroll
    for (int g = 0; g < 4; ++g) {
#pragma unroll
      for (int t = 0; t < 2; ++t) {
#pragma unroll
        for (int r = 0; r < 4; ++r) {
          mbuf[(g * 16 + kg * 4 + r) * 128 + w * 32 + t * 16 + col] = (f16_t)acc[g][t][r];
        }
      }
    }
  }
  __syncthreads();
  // quad 0: merge + normalize + write out[n][h*128+o]
  if (wq == 0) {
#pragma unroll
    for (int g = 0; g < 4; ++g) {
#pragma unroll
      for (int r = 0; r < 4; ++r) {
        const int row = g * 16 + kg * 4 + r;
        const float inv = __builtin_amdgcn_rcpf(lds_den[0][row] + lds_den[1][row]);
        float* op = out + (size_t)(i0 + row) * 1024 + h * 128 + w * 32;
#pragma unroll
        for (int t = 0; t < 2; ++t) {
          const float v = acc[g][t][r] + (float)mbuf[row * 128 + w * 32 + t * 16 + col];
          op[t * 16 + col] = v * inv;
        }
      }
    }
  }
}

extern "C" void kernel_launch(void* const* d_in, const int* in_sizes, int n_in,
                              void* d_out, int out_size, void* d_ws, size_t ws_size,
                              hipStream_t stream) {
  const float* x = (const float*)d_in[0];
  const int* adj = (const int*)d_in[1];
  const float* W = (const float*)d_in[2];
  const float* a_src = (const float*)d_in[3];
  const float* a_dst = (const float*)d_in[4];
  float* out = (float*)d_out;
  char* ws = (char*)d_ws;
  // workspace layout (bytes):
  //   WhB   swizzled f16          : 0        .. 8388608
  //   xh    [4096][512] f16       : 8388608  .. 12582912
  //   WT    [8][128][512] f16     : 12582912 .. 13631488
  //   mask  [4096][512] u8        : 13631488 .. 15728640
  //   EA/EA2/EB/EB2 [8][4096] f16 : 15728640 .. 15990784 (4 x 64KB)
  f16_t* WhB = (f16_t*)(ws);
  f16_t* xh = (f16_t*)(ws + 8388608);
  f16_t* WT = (f16_t*)(ws + 12582912);
  unsigned char* mask8 = (unsigned char*)(ws + 13631488);
  f16_t* EA = (f16_t*)(ws + 15728640);
  f16_t* EA2 = (f16_t*)(ws + 15794176);
  f16_t* EB = (f16_t*)(ws + 15859712);
  f16_t* EB2 = (f16_t*)(ws + 15925248);

  k_cvt<<<3072, 256, 0, stream>>>(x, xh, W, WT);
  k_gemm_pack<<<8704, 256, 0, stream>>>(xh, WT, a_src, a_dst, WhB, EA, EA2, EB, EB2,
                                        adj, mask8);
  k_pv<<<512, 512, 0, stream>>>(WhB, EA, EA2, EB, EB2, mask8, out);
}

// Round 24
// 82.635 us; speedup vs baseline: 1.6408x; 1.2392x over previous
//
#include <hip/hip_runtime.h>

#define LOG2E 1.44269504088896340736f

typedef _Float16 f16_t;
typedef f16_t f16x2 __attribute__((ext_vector_type(2)));
typedef f16_t f16x4 __attribute__((ext_vector_type(4)));
typedef f16_t f16x8 __attribute__((ext_vector_type(8)));
typedef float f32x4 __attribute__((ext_vector_type(4)));

// Problem constants: N=4096 nodes, F_in=512, F_out=128, H=8 heads.

// ---- K0: cvt to MFMA-FRAGMENT-ORDER buffers ----
// xF: A-frag layout. Element (n,k) -> xF[((n>>4)*16 + (k>>5))*512 +
//     ((n&15) + ((k>>3)&3)*16)*8 + (k&7)]  -- so a wave's A-load for
//     (16-row tile, 32-k chunk) is ONE contiguous 1KB read (lane*8).
// wF: B-frag layout. Element (h,o,k) -> wF[((h*8 + (o>>4))*16 + (k>>5))*512
//     + ((o&15) + ((k>>3)&3)*16)*8 + (k&7)].
// This kills the GEMM's 16-line gathers (TA-bound, ~25us) at zero extra
// traffic: k_cvt already touches every element; only write addrs change.
__global__ __launch_bounds__(256) void k_cvt(const float* __restrict__ x,
                                             f16_t* __restrict__ xF,
                                             const float* __restrict__ W,
                                             f16_t* __restrict__ wF) {
  const int bx = blockIdx.x;
  if (bx < 1024) {  // x fp32 -> fp16 fragment order
    const int t = bx * 256 + threadIdx.x;  // 262144: n = t>>6, k0 = (t&63)*8
    const int n = t >> 6, k0 = (t & 63) * 8;
    const f32x4 a = *(const f32x4*)(x + n * 512 + k0);
    const f32x4 b = *(const f32x4*)(x + n * 512 + k0 + 4);
    f16x8 o;
#pragma unroll
    for (int i = 0; i < 4; ++i) { o[i] = (f16_t)a[i]; o[i + 4] = (f16_t)b[i]; }
    const int lanei = (n & 15) + ((k0 >> 3) & 3) * 16;
    *(f16x8*)(xF + (((n >> 4) * 16 + (k0 >> 5)) * 64 + lanei) * 8) = o;
  } else {  // W [h][k][o] fp32 -> wF fragment order
    const int t = (bx - 1024) * 256 + threadIdx.x;  // 524288
    const int k = t & 511, o = (t >> 9) & 127, h = t >> 16;
    const int lanei = (o & 15) + ((k >> 3) & 3) * 16;
    wF[(((h * 8 + (o >> 4)) * 16 + (k >> 5)) * 64 + lanei) * 8 + (k & 7)] =
        (f16_t)W[((h << 9) + k) * 128 + o];
  }
}

// ---- K1: FUSED Wh-GEMM + adjacency pack (GEMM-first order) ----
// Blocks 0..511: Wh GEMM reading fragment-order xF/wF -- every A/B load is
// a contiguous 1KB wave read (was a 16-cache-line gather). Blocks
// 512..8703: pack adj (64MB->2MB), fills CUs around the GEMM blocks.
__global__ __launch_bounds__(256) void k_gemm_pack(const f16_t* __restrict__ xF,
                                                   const f16_t* __restrict__ wF,
                                                   const float* __restrict__ a_src,
                                                   const float* __restrict__ a_dst,
                                                   f16_t* __restrict__ WhB,
                                                   f16_t* __restrict__ EA,
                                                   f16_t* __restrict__ EA2,
                                                   f16_t* __restrict__ EB,
                                                   f16_t* __restrict__ EB2,
                                                   const int* __restrict__ adj,
                                                   unsigned char* __restrict__ mask8) {
  const int bx = blockIdx.x;
  if (bx >= 512) {  // ---- adjacency pack ----
    const int t = (bx - 512) * 256 + threadIdx.x;
    const int4 a = ((const int4*)adj)[t * 2];
    const int4 b = ((const int4*)adj)[t * 2 + 1];
    unsigned v = (a.x > 0) | ((a.y > 0) << 1) | ((a.z > 0) << 2) | ((a.w > 0) << 3) |
                 ((b.x > 0) << 4) | ((b.y > 0) << 5) | ((b.z > 0) << 6) | ((b.w > 0) << 7);
    mask8[t] = (unsigned char)v;
    return;
  }
  // ---- Wh GEMM (h-first flatten for XCD spread) ----
  const int h = bx & 7;
  const int n0 = (bx >> 3) * 64;
  const int lane = threadIdx.x & 63;
  const int w = threadIdx.x >> 6;
  const int col = lane & 15;
  const int kg = lane >> 4;
  const f16_t* xA = xF + (size_t)((n0 >> 4) + w) * 8192 + lane * 8;  // 16 chunks x 512
  const f16_t* wB = wF + ((size_t)h << 16) + lane * 8;
  f32x4 acc[8] = {};
  for (int c = 0; c < 16; ++c) {
    const f16x8 a = *(const f16x8*)(xA + c * 512);
#pragma unroll
    for (int ot = 0; ot < 8; ++ot) {
      const f16x8 b = *(const f16x8*)(wB + (ot * 16 + c) * 512);
      acc[ot] = __builtin_amdgcn_mfma_f32_16x16x32_f16(a, b, acc[ot], 0, 0, 0);
    }
  }
  float ps[4] = {0.f, 0.f, 0.f, 0.f}, pd[4] = {0.f, 0.f, 0.f, 0.f};
#pragma unroll
  for (int ot = 0; ot < 8; ++ot) {
    const float as = a_src[h * 128 + ot * 16 + col];
    const float ad = a_dst[h * 128 + ot * 16 + col];
#pragma unroll
    for (int r = 0; r < 4; ++r) { ps[r] += acc[ot][r] * as; pd[r] += acc[ot][r] * ad; }
  }
#pragma unroll
  for (int m = 1; m < 16; m <<= 1) {
#pragma unroll
    for (int r = 0; r < 4; ++r) {
      ps[r] += __shfl_xor(ps[r], m, 64);
      pd[r] += __shfl_xor(pd[r], m, 64);
    }
  }
  const int nb = n0 + w * 16 + kg * 4;  // node index of acc[.][0]
  if (col == 0) {
#pragma unroll
    for (int r = 0; r < 4; ++r) {
      const float fs = ps[r] * LOG2E;
      const float fd = pd[r] * LOG2E;
      const int idx = h * 4096 + nb + r;
      EA[idx] = (f16_t)__builtin_amdgcn_exp2f(fs);
      EA2[idx] = (f16_t)__builtin_amdgcn_exp2f(0.2f * fs);
      EB[idx] = (f16_t)__builtin_amdgcn_exp2f(fd);
      EB2[idx] = (f16_t)__builtin_amdgcn_exp2f(0.2f * fd);
    }
  }
  // swizzled store: (h,o,j) -> WhB[((h*128+j/32)*8+o/16)*512 + ((j>>3)&3)*128 + (o&15)*8 + (j&7)]
  const int jb = nb >> 5;
  const int kgt = (nb >> 3) & 3;
  const int e0 = nb & 4;
  const size_t base = ((size_t)(h * 128 + jb) * 8) * 512 + kgt * 128 + col * 8 + e0;
#pragma unroll
  for (int ot = 0; ot < 8; ++ot) {
    f16x4 v;
#pragma unroll
    for (int r = 0; r < 4; ++r) v[r] = (f16_t)acc[ot][r];
    *(f16x4*)(WhB + base + ot * 512) = v;
  }
}

// P-generation: p = max(EA_i*EB_j, EA2_i*EB2_j) * m_ij (piecewise exp of
// LeakyReLU), packed fp16, mask via 16-entry nibble LUTs.
#define GEN_P(dst, mw, vb, vb2)                                                            \
  {                                                                                        \
    const unsigned bb_ = (mw) & 255u;                                                      \
    const f16x4 lmL_ = *(const f16x4*)(&lut4[bb_ & 15u][0]);                               \
    const f16x4 lmH_ = *(const f16x4*)(&lut4[bb_ >> 4][0]);                                \
    const f16x2* vp_ = (const f16x2*)&(vb);                                                \
    const f16x2* v2p_ = (const f16x2*)&(vb2);                                              \
    ((f16x2*)&(dst))[0] = __builtin_elementwise_max(As * vp_[0], A2s * v2p_[0]) * ((const f16x2*)&lmL_)[0]; \
    ((f16x2*)&(dst))[1] = __builtin_elementwise_max(As * vp_[1], A2s * v2p_[1]) * ((const f16x2*)&lmL_)[1]; \
    ((f16x2*)&(dst))[2] = __builtin_elementwise_max(As * vp_[2], A2s * v2p_[2]) * ((const f16x2*)&lmH_)[0]; \
    ((f16x2*)&(dst))[3] = __builtin_elementwise_max(As * vp_[3], A2s * v2p_[3]) * ((const f16x2*)&lmH_)[1]; \
  }

// ---- K2: masked softmax + PV, fused merge (champion body, byte-identical) ----
__global__ __launch_bounds__(512, 4) void k_pv(const f16_t* __restrict__ WhB,
                                               const f16_t* __restrict__ EA,
                                               const f16_t* __restrict__ EA2,
                                               const f16_t* __restrict__ EB,
                                               const f16_t* __restrict__ EB2,
                                               const unsigned char* __restrict__ mask,
                                               float* __restrict__ out) {
  __shared__ __align__(16) unsigned char lds_mask[64 * 528];       // 33.8 KB
  __shared__ __align__(16) unsigned short lut4[16][4];
  __shared__ __align__(16) f16_t lds_P[2][2][4][512];              // 16 KB; reused as merge buf
  __shared__ float lds_den[2][64];
  const int bx = blockIdx.x;
  const int h = bx & 7;            // head -> XCD round-robin
  const int i0 = (bx >> 3) * 64;   // 64-row i-tile
  const int tid = threadIdx.x;
  {
    if (tid < 16) {
#pragma unroll
      for (int e = 0; e < 4; ++e) lut4[tid][e] = ((tid >> e) & 1) ? 0x3C00 : 0;
    }
    const int row = tid >> 3, ch = (tid & 7) * 64;
    const uint4* src = (const uint4*)(mask + (size_t)(i0 + row) * 512 + ch);
    uint4* dst = (uint4*)(lds_mask + row * 528 + ch);
#pragma unroll
    for (int i = 0; i < 4; ++i) dst[i] = src[i];
  }
  __syncthreads();
  const int wq = tid >> 8;         // j-slice quad (0..1)
  const int w = (tid >> 6) & 3;    // row-group owner (P-gen) AND o-quarter
  const int lane = tid & 63;
  const int col = lane & 15, kg = lane >> 4;
  const int sh = kg * 8;
  const int jbeg = wq * 2048;
  f16x2 As, A2s;
  {
    const f16_t a = EA[h * 4096 + i0 + w * 16 + col];
    const f16_t a2 = EA2[h * 4096 + i0 + w * 16 + col];
    As = (f16x2){a, a};
    A2s = (f16x2){a2, a2};
  }
  f16x8 ones8;
#pragma unroll
  for (int e = 0; e < 8; ++e) ones8[e] = (f16_t)1.0f;
  const unsigned char* mrow = lds_mask + (w * 16 + col) * 528 + wq * 256;
  const f16_t* EBp = EB + h * 4096 + jbeg + kg * 8;
  const f16_t* EB2p = EB2 + h * 4096 + jbeg + kg * 8;
  const f16_t* whB = WhB + ((size_t)h << 19) + (size_t)(jbeg >> 5) * 4096 + (2 * w) * 512 + lane * 8;
  f32x4 acc[4][2] = {};
  f32x4 den_acc = {};
  uint4 mdc = *(const uint4*)(mrow);
  f16x8 cb0 = *(const f16x8*)(whB);
  f16x8 cb1 = *(const f16x8*)(whB + 512);
  f16x8 evb = *(const f16x8*)(EBp + 32);
  f16x8 evb2 = *(const f16x8*)(EB2p + 32);
  {
    const f16x8 gvb = *(const f16x8*)(EBp);
    const f16x8 gvb2 = *(const f16x8*)(EB2p);
    f16x8 a0;
    GEN_P(a0, mdc.x >> sh, gvb, gvb2);
    den_acc = __builtin_amdgcn_mfma_f32_16x16x32_f16(a0, ones8, den_acc, 0, 0, 0);
    *(f16x8*)(&lds_P[wq][0][w][lane * 8]) = a0;
  }
  __syncthreads();
  f16x8 aCur;
  for (int it4 = 0; it4 < 16; ++it4) {
    const uint4 mdn = *(const uint4*)(mrow + ((it4 + 1) & 15) * 16);
#pragma unroll
    for (int q = 0; q < 4; ++q) {
      const int it = it4 * 4 + q;
      const int buf = q & 1;
      const f16x8 p0 = *(const f16x8*)(&lds_P[wq][buf][0][lane * 8]);
      const f16x8 p1 = *(const f16x8*)(&lds_P[wq][buf][1][lane * 8]);
      const f16x8 p2 = *(const f16x8*)(&lds_P[wq][buf][2][lane * 8]);
      const f16x8 p3 = *(const f16x8*)(&lds_P[wq][buf][3][lane * 8]);
      const f16_t* wpn = whB + (size_t)(it + 1) * 4096;
      const f16x8 nb0 = *(const f16x8*)(wpn);
      const f16x8 nb1 = *(const f16x8*)(wpn + 512);
      acc[0][0] = __builtin_amdgcn_mfma_f32_16x16x32_f16(p0, cb0, acc[0][0], 0, 0, 0);
      acc[0][1] = __builtin_amdgcn_mfma_f32_16x16x32_f16(p0, cb1, acc[0][1], 0, 0, 0);
      acc[1][0] = __builtin_amdgcn_mfma_f32_16x16x32_f16(p1, cb0, acc[1][0], 0, 0, 0);
      acc[1][1] = __builtin_amdgcn_mfma_f32_16x16x32_f16(p1, cb1, acc[1][1], 0, 0, 0);
      acc[2][0] = __builtin_amdgcn_mfma_f32_16x16x32_f16(p2, cb0, acc[2][0], 0, 0, 0);
      acc[2][1] = __builtin_amdgcn_mfma_f32_16x16x32_f16(p2, cb1, acc[2][1], 0, 0, 0);
      acc[3][0] = __builtin_amdgcn_mfma_f32_16x16x32_f16(p3, cb0, acc[3][0], 0, 0, 0);
      acc[3][1] = __builtin_amdgcn_mfma_f32_16x16x32_f16(p3, cb1, acc[3][1], 0, 0, 0);
      const unsigned mw = ((q == 0) ? mdc.y : (q == 1) ? mdc.z : (q == 2) ? mdc.w : mdn.x) >> sh;
      GEN_P(aCur, mw, evb, evb2);
      *(f16x8*)(&lds_P[wq][buf ^ 1][w][lane * 8]) = aCur;
      if (q < 3 || it4 < 15)
        den_acc = __builtin_amdgcn_mfma_f32_16x16x32_f16(aCur, ones8, den_acc, 0, 0, 0);
      const f16x8 nevb = *(const f16x8*)(EBp + (it + 2) * 32);
      const f16x8 nevb2 = *(const f16x8*)(EB2p + (it + 2) * 32);
      __syncthreads();
      cb0 = nb0; cb1 = nb1; evb = nevb; evb2 = nevb2;
    }
    mdc = mdn;
  }
  if (col == 0) {
#pragma unroll
    for (int r = 0; r < 4; ++r) lds_den[wq][w * 16 + kg * 4 + r] = den_acc[r];
  }
  f16_t* mbuf = (f16_t*)lds_P;
  if (wq == 1) {
#pragma unroll
    for (int g = 0; g < 4; ++g) {
#pragma unroll
      for (int t = 0; t < 2; ++t) {
#pragma unroll
        for (int r = 0; r < 4; ++r) {
          mbuf[(g * 16 + kg * 4 + r) * 128 + w * 32 + t * 16 + col] = (f16_t)acc[g][t][r];
        }
      }
    }
  }
  __syncthreads();
  if (wq == 0) {
#pragma unroll
    for (int g = 0; g < 4; ++g) {
#pragma unroll
      for (int r = 0; r < 4; ++r) {
        const int row = g * 16 + kg * 4 + r;
        const float inv = __builtin_amdgcn_rcpf(lds_den[0][row] + lds_den[1][row]);
        float* op = out + (size_t)(i0 + row) * 1024 + h * 128 + w * 32;
#pragma unroll
        for (int t = 0; t < 2; ++t) {
          const float v = acc[g][t][r] + (float)mbuf[row * 128 + w * 32 + t * 16 + col];
          op[t * 16 + col] = v * inv;
        }
      }
    }
  }
}

extern "C" void kernel_launch(void* const* d_in, const int* in_sizes, int n_in,
                              void* d_out, int out_size, void* d_ws, size_t ws_size,
                              hipStream_t stream) {
  const float* x = (const float*)d_in[0];
  const int* adj = (const int*)d_in[1];
  const float* W = (const float*)d_in[2];
  const float* a_src = (const float*)d_in[3];
  const float* a_dst = (const float*)d_in[4];
  float* out = (float*)d_out;
  char* ws = (char*)d_ws;
  // workspace layout (bytes):
  //   WhB   swizzled f16          : 0        .. 8388608
  //   xF    frag-order f16        : 8388608  .. 12582912
  //   wF    frag-order f16        : 12582912 .. 13631488
  //   mask  [4096][512] u8        : 13631488 .. 15728640
  //   EA/EA2/EB/EB2 [8][4096] f16 : 15728640 .. 15990784 (4 x 64KB)
  f16_t* WhB = (f16_t*)(ws);
  f16_t* xF = (f16_t*)(ws + 8388608);
  f16_t* wF = (f16_t*)(ws + 12582912);
  unsigned char* mask8 = (unsigned char*)(ws + 13631488);
  f16_t* EA = (f16_t*)(ws + 15728640);
  f16_t* EA2 = (f16_t*)(ws + 15794176);
  f16_t* EB = (f16_t*)(ws + 15859712);
  f16_t* EB2 = (f16_t*)(ws + 15925248);

  k_cvt<<<3072, 256, 0, stream>>>(x, xF, W, wF);
  k_gemm_pack<<<8704, 256, 0, stream>>>(xF, wF, a_src, a_dst, WhB, EA, EA2, EB, EB2,
                                        adj, mask8);
  k_pv<<<512, 512, 0, stream>>>(WhB, EA, EA2, EB, EB2, mask8, out);
}

// Round 26
// 79.986 us; speedup vs baseline: 1.6952x; 1.0331x over previous
//
#include <hip/hip_runtime.h>

#define LOG2E 1.44269504088896340736f

typedef _Float16 f16_t;
typedef f16_t f16x2 __attribute__((ext_vector_type(2)));
typedef f16_t f16x4 __attribute__((ext_vector_type(4)));
typedef f16_t f16x8 __attribute__((ext_vector_type(8)));
typedef float f32x4 __attribute__((ext_vector_type(4)));

// Problem constants: N=4096 nodes, F_in=512, F_out=128, H=8 heads.

// ---- K0: cvt to MFMA-FRAGMENT-ORDER buffers ----
// xF: A-frag layout. Element (n,k) -> xF[((n>>4)*16 + (k>>5))*512 +
//     ((n&15) + ((k>>3)&3)*16)*8 + (k&7)]  -- a wave's A-load for a
//     (16-row, 32-k) tile is ONE contiguous 1KB read. Same for wF.
// Killed the GEMM's 16-line gathers (R24: total 102.4 -> 82.6us).
__global__ __launch_bounds__(256) void k_cvt(const float* __restrict__ x,
                                             f16_t* __restrict__ xF,
                                             const float* __restrict__ W,
                                             f16_t* __restrict__ wF) {
  const int bx = blockIdx.x;
  if (bx < 1024) {  // x fp32 -> fp16 fragment order
    const int t = bx * 256 + threadIdx.x;  // 262144: n = t>>6, k0 = (t&63)*8
    const int n = t >> 6, k0 = (t & 63) * 8;
    const f32x4 a = *(const f32x4*)(x + n * 512 + k0);
    const f32x4 b = *(const f32x4*)(x + n * 512 + k0 + 4);
    f16x8 o;
#pragma unroll
    for (int i = 0; i < 4; ++i) { o[i] = (f16_t)a[i]; o[i + 4] = (f16_t)b[i]; }
    const int lanei = (n & 15) + ((k0 >> 3) & 3) * 16;
    *(f16x8*)(xF + (((n >> 4) * 16 + (k0 >> 5)) * 64 + lanei) * 8) = o;
  } else {  // W [h][k][o] fp32 -> wF fragment order
    const int t = (bx - 1024) * 256 + threadIdx.x;  // 524288
    const int k = t & 511, o = (t >> 9) & 127, h = t >> 16;
    const int lanei = (o & 15) + ((k >> 3) & 3) * 16;
    wF[(((h * 8 + (o >> 4)) * 16 + (k >> 5)) * 64 + lanei) * 8 + (k & 7)] =
        (f16_t)W[((h << 9) + k) * 128 + o];
  }
}

// ---- K1: FUSED Wh-GEMM + adjacency pack (GEMM-first order) ----
__global__ __launch_bounds__(256) void k_gemm_pack(const f16_t* __restrict__ xF,
                                                   const f16_t* __restrict__ wF,
                                                   const float* __restrict__ a_src,
                                                   const float* __restrict__ a_dst,
                                                   f16_t* __restrict__ WhB,
                                                   f16_t* __restrict__ EA,
                                                   f16_t* __restrict__ EA2,
                                                   f16_t* __restrict__ EB,
                                                   f16_t* __restrict__ EB2,
                                                   const int* __restrict__ adj,
                                                   unsigned char* __restrict__ mask8) {
  const int bx = blockIdx.x;
  if (bx >= 512) {  // ---- adjacency pack ----
    const int t = (bx - 512) * 256 + threadIdx.x;
    const int4 a = ((const int4*)adj)[t * 2];
    const int4 b = ((const int4*)adj)[t * 2 + 1];
    unsigned v = (a.x > 0) | ((a.y > 0) << 1) | ((a.z > 0) << 2) | ((a.w > 0) << 3) |
                 ((b.x > 0) << 4) | ((b.y > 0) << 5) | ((b.z > 0) << 6) | ((b.w > 0) << 7);
    mask8[t] = (unsigned char)v;
    return;
  }
  // ---- Wh GEMM (h-first flatten for XCD spread) ----
  const int h = bx & 7;
  const int n0 = (bx >> 3) * 64;
  const int lane = threadIdx.x & 63;
  const int w = threadIdx.x >> 6;
  const int col = lane & 15;
  const int kg = lane >> 4;
  const f16_t* xA = xF + (size_t)((n0 >> 4) + w) * 8192 + lane * 8;  // 16 chunks x 512
  const f16_t* wB = wF + ((size_t)h << 16) + lane * 8;
  f32x4 acc[8] = {};
  for (int c = 0; c < 16; ++c) {
    const f16x8 a = *(const f16x8*)(xA + c * 512);
#pragma unroll
    for (int ot = 0; ot < 8; ++ot) {
      const f16x8 b = *(const f16x8*)(wB + (ot * 16 + c) * 512);
      acc[ot] = __builtin_amdgcn_mfma_f32_16x16x32_f16(a, b, acc[ot], 0, 0, 0);
    }
  }
  float ps[4] = {0.f, 0.f, 0.f, 0.f}, pd[4] = {0.f, 0.f, 0.f, 0.f};
#pragma unroll
  for (int ot = 0; ot < 8; ++ot) {
    const float as = a_src[h * 128 + ot * 16 + col];
    const float ad = a_dst[h * 128 + ot * 16 + col];
#pragma unroll
    for (int r = 0; r < 4; ++r) { ps[r] += acc[ot][r] * as; pd[r] += acc[ot][r] * ad; }
  }
#pragma unroll
  for (int m = 1; m < 16; m <<= 1) {
#pragma unroll
    for (int r = 0; r < 4; ++r) {
      ps[r] += __shfl_xor(ps[r], m, 64);
      pd[r] += __shfl_xor(pd[r], m, 64);
    }
  }
  const int nb = n0 + w * 16 + kg * 4;  // node index of acc[.][0]
  if (col == 0) {
#pragma unroll
    for (int r = 0; r < 4; ++r) {
      const float fs = ps[r] * LOG2E;
      const float fd = pd[r] * LOG2E;
      const int idx = h * 4096 + nb + r;
      EA[idx] = (f16_t)__builtin_amdgcn_exp2f(fs);
      EA2[idx] = (f16_t)__builtin_amdgcn_exp2f(0.2f * fs);
      EB[idx] = (f16_t)__builtin_amdgcn_exp2f(fd);
      EB2[idx] = (f16_t)__builtin_amdgcn_exp2f(0.2f * fd);
    }
  }
  // swizzled store: (h,o,j) -> WhB[((h*128+j/32)*8+o/16)*512 + ((j>>3)&3)*128 + (o&15)*8 + (j&7)]
  const int jb = nb >> 5;
  const int kgt = (nb >> 3) & 3;
  const int e0 = nb & 4;
  const size_t base = ((size_t)(h * 128 + jb) * 8) * 512 + kgt * 128 + col * 8 + e0;
#pragma unroll
  for (int ot = 0; ot < 8; ++ot) {
    f16x4 v;
#pragma unroll
    for (int r = 0; r < 4; ++r) v[r] = (f16_t)acc[ot][r];
    *(f16x4*)(WhB + base + ot * 512) = v;
  }
}

// P-generation: p = max(EA_i*EB_j, EA2_i*EB2_j) * m_ij (piecewise exp of
// LeakyReLU), packed fp16, mask via 16-entry nibble LUTs.
#define GEN_P(dst, mw, vb, vb2)                                                            \
  {                                                                                        \
    const unsigned bb_ = (mw) & 255u;                                                      \
    const f16x4 lmL_ = *(const f16x4*)(&lut4[bb_ & 15u][0]);                               \
    const f16x4 lmH_ = *(const f16x4*)(&lut4[bb_ >> 4][0]);                                \
    const f16x2* vp_ = (const f16x2*)&(vb);                                                \
    const f16x2* v2p_ = (const f16x2*)&(vb2);                                              \
    ((f16x2*)&(dst))[0] = __builtin_elementwise_max(As * vp_[0], A2s * v2p_[0]) * ((const f16x2*)&lmL_)[0]; \
    ((f16x2*)&(dst))[1] = __builtin_elementwise_max(As * vp_[1], A2s * v2p_[1]) * ((const f16x2*)&lmL_)[1]; \
    ((f16x2*)&(dst))[2] = __builtin_elementwise_max(As * vp_[2], A2s * v2p_[2]) * ((const f16x2*)&lmH_)[0]; \
    ((f16x2*)&(dst))[3] = __builtin_elementwise_max(As * vp_[3], A2s * v2p_[3]) * ((const f16x2*)&lmH_)[1]; \
  }

// ---- K2: masked softmax + PV, fused merge (champion body + T5 setprio) ----
// mbuf pitch REVERTED to 128 (R25 bug: pitch 132 -> 8448 f16 overflows the
// 8192-f16 lds_P region into lds_den). T5 setprio kept, now isolated.
__global__ __launch_bounds__(512, 4) void k_pv(const f16_t* __restrict__ WhB,
                                               const f16_t* __restrict__ EA,
                                               const f16_t* __restrict__ EA2,
                                               const f16_t* __restrict__ EB,
                                               const f16_t* __restrict__ EB2,
                                               const unsigned char* __restrict__ mask,
                                               float* __restrict__ out) {
  __shared__ __align__(16) unsigned char lds_mask[64 * 528];       // 33.8 KB
  __shared__ __align__(16) unsigned short lut4[16][4];
  __shared__ __align__(16) f16_t lds_P[2][2][4][512];              // 16 KB; reused as merge buf
  __shared__ float lds_den[2][64];
  const int bx = blockIdx.x;
  const int h = bx & 7;            // head -> XCD round-robin
  const int i0 = (bx >> 3) * 64;   // 64-row i-tile
  const int tid = threadIdx.x;
  {
    if (tid < 16) {
#pragma unroll
      for (int e = 0; e < 4; ++e) lut4[tid][e] = ((tid >> e) & 1) ? 0x3C00 : 0;
    }
    const int row = tid >> 3, ch = (tid & 7) * 64;
    const uint4* src = (const uint4*)(mask + (size_t)(i0 + row) * 512 + ch);
    uint4* dst = (uint4*)(lds_mask + row * 528 + ch);
#pragma unroll
    for (int i = 0; i < 4; ++i) dst[i] = src[i];
  }
  __syncthreads();
  const int wq = tid >> 8;         // j-slice quad (0..1)
  const int w = (tid >> 6) & 3;    // row-group owner (P-gen) AND o-quarter
  const int lane = tid & 63;
  const int col = lane & 15, kg = lane >> 4;
  const int sh = kg * 8;
  const int jbeg = wq * 2048;
  f16x2 As, A2s;
  {
    const f16_t a = EA[h * 4096 + i0 + w * 16 + col];
    const f16_t a2 = EA2[h * 4096 + i0 + w * 16 + col];
    As = (f16x2){a, a};
    A2s = (f16x2){a2, a2};
  }
  f16x8 ones8;
#pragma unroll
  for (int e = 0; e < 8; ++e) ones8[e] = (f16_t)1.0f;
  const unsigned char* mrow = lds_mask + (w * 16 + col) * 528 + wq * 256;
  const f16_t* EBp = EB + h * 4096 + jbeg + kg * 8;
  const f16_t* EB2p = EB2 + h * 4096 + jbeg + kg * 8;
  const f16_t* whB = WhB + ((size_t)h << 19) + (size_t)(jbeg >> 5) * 4096 + (2 * w) * 512 + lane * 8;
  f32x4 acc[4][2] = {};
  f32x4 den_acc = {};
  uint4 mdc = *(const uint4*)(mrow);
  f16x8 cb0 = *(const f16x8*)(whB);
  f16x8 cb1 = *(const f16x8*)(whB + 512);
  f16x8 evb = *(const f16x8*)(EBp + 32);
  f16x8 evb2 = *(const f16x8*)(EB2p + 32);
  {
    const f16x8 gvb = *(const f16x8*)(EBp);
    const f16x8 gvb2 = *(const f16x8*)(EB2p);
    f16x8 a0;
    GEN_P(a0, mdc.x >> sh, gvb, gvb2);
    den_acc = __builtin_amdgcn_mfma_f32_16x16x32_f16(a0, ones8, den_acc, 0, 0, 0);
    *(f16x8*)(&lds_P[wq][0][w][lane * 8]) = a0;
  }
  __syncthreads();
  f16x8 aCur;
  for (int it4 = 0; it4 < 16; ++it4) {
    const uint4 mdn = *(const uint4*)(mrow + ((it4 + 1) & 15) * 16);
#pragma unroll
    for (int q = 0; q < 4; ++q) {
      const int it = it4 * 4 + q;
      const int buf = q & 1;
      const f16x8 p0 = *(const f16x8*)(&lds_P[wq][buf][0][lane * 8]);
      const f16x8 p1 = *(const f16x8*)(&lds_P[wq][buf][1][lane * 8]);
      const f16x8 p2 = *(const f16x8*)(&lds_P[wq][buf][2][lane * 8]);
      const f16x8 p3 = *(const f16x8*)(&lds_P[wq][buf][3][lane * 8]);
      const f16_t* wpn = whB + (size_t)(it + 1) * 4096;
      const f16x8 nb0 = *(const f16x8*)(wpn);
      const f16x8 nb1 = *(const f16x8*)(wpn + 512);
      __builtin_amdgcn_s_setprio(1);
      acc[0][0] = __builtin_amdgcn_mfma_f32_16x16x32_f16(p0, cb0, acc[0][0], 0, 0, 0);
      acc[0][1] = __builtin_amdgcn_mfma_f32_16x16x32_f16(p0, cb1, acc[0][1], 0, 0, 0);
      acc[1][0] = __builtin_amdgcn_mfma_f32_16x16x32_f16(p1, cb0, acc[1][0], 0, 0, 0);
      acc[1][1] = __builtin_amdgcn_mfma_f32_16x16x32_f16(p1, cb1, acc[1][1], 0, 0, 0);
      acc[2][0] = __builtin_amdgcn_mfma_f32_16x16x32_f16(p2, cb0, acc[2][0], 0, 0, 0);
      acc[2][1] = __builtin_amdgcn_mfma_f32_16x16x32_f16(p2, cb1, acc[2][1], 0, 0, 0);
      acc[3][0] = __builtin_amdgcn_mfma_f32_16x16x32_f16(p3, cb0, acc[3][0], 0, 0, 0);
      acc[3][1] = __builtin_amdgcn_mfma_f32_16x16x32_f16(p3, cb1, acc[3][1], 0, 0, 0);
      __builtin_amdgcn_s_setprio(0);
      const unsigned mw = ((q == 0) ? mdc.y : (q == 1) ? mdc.z : (q == 2) ? mdc.w : mdn.x) >> sh;
      GEN_P(aCur, mw, evb, evb2);
      *(f16x8*)(&lds_P[wq][buf ^ 1][w][lane * 8]) = aCur;
      if (q < 3 || it4 < 15)
        den_acc = __builtin_amdgcn_mfma_f32_16x16x32_f16(aCur, ones8, den_acc, 0, 0, 0);
      const f16x8 nevb = *(const f16x8*)(EBp + (it + 2) * 32);
      const f16x8 nevb2 = *(const f16x8*)(EB2p + (it + 2) * 32);
      __syncthreads();
      cb0 = nb0; cb1 = nb1; evb = nevb; evb2 = nevb2;
    }
    mdc = mdn;
  }
  if (col == 0) {
#pragma unroll
    for (int r = 0; r < 4; ++r) lds_den[wq][w * 16 + kg * 4 + r] = den_acc[r];
  }
  // quad 1 dumps acc (f16) into retired lds_P region as [64][128] (exact fit)
  f16_t* mbuf = (f16_t*)lds_P;
  if (wq == 1) {
#pragma unroll
    for (int g = 0; g < 4; ++g) {
#pragma unroll
      for (int t = 0; t < 2; ++t) {
#pragma unroll
        for (int r = 0; r < 4; ++r) {
          mbuf[(g * 16 + kg * 4 + r) * 128 + w * 32 + t * 16 + col] = (f16_t)acc[g][t][r];
        }
      }
    }
  }
  __syncthreads();
  if (wq == 0) {
#pragma unroll
    for (int g = 0; g < 4; ++g) {
#pragma unroll
      for (int r = 0; r < 4; ++r) {
        const int row = g * 16 + kg * 4 + r;
        const float inv = __builtin_amdgcn_rcpf(lds_den[0][row] + lds_den[1][row]);
        float* op = out + (size_t)(i0 + row) * 1024 + h * 128 + w * 32;
#pragma unroll
        for (int t = 0; t < 2; ++t) {
          const float v = acc[g][t][r] + (float)mbuf[row * 128 + w * 32 + t * 16 + col];
          op[t * 16 + col] = v * inv;
        }
      }
    }
  }
}

extern "C" void kernel_launch(void* const* d_in, const int* in_sizes, int n_in,
                              void* d_out, int out_size, void* d_ws, size_t ws_size,
                              hipStream_t stream) {
  const float* x = (const float*)d_in[0];
  const int* adj = (const int*)d_in[1];
  const float* W = (const float*)d_in[2];
  const float* a_src = (const float*)d_in[3];
  const float* a_dst = (const float*)d_in[4];
  float* out = (float*)d_out;
  char* ws = (char*)d_ws;
  // workspace layout (bytes):
  //   WhB   swizzled f16          : 0        .. 8388608
  //   xF    frag-order f16        : 8388608  .. 12582912
  //   wF    frag-order f16        : 12582912 .. 13631488
  //   mask  [4096][512] u8        : 13631488 .. 15728640
  //   EA/EA2/EB/EB2 [8][4096] f16 : 15728640 .. 15990784 (4 x 64KB)
  f16_t* WhB = (f16_t*)(ws);
  f16_t* xF = (f16_t*)(ws + 8388608);
  f16_t* wF = (f16_t*)(ws + 12582912);
  unsigned char* mask8 = (unsigned char*)(ws + 13631488);
  f16_t* EA = (f16_t*)(ws + 15728640);
  f16_t* EA2 = (f16_t*)(ws + 15794176);
  f16_t* EB = (f16_t*)(ws + 15859712);
  f16_t* EB2 = (f16_t*)(ws + 15925248);

  k_cvt<<<3072, 256, 0, stream>>>(x, xF, W, wF);
  k_gemm_pack<<<8704, 256, 0, stream>>>(xF, wF, a_src, a_dst, WhB, EA, EA2, EB, EB2,
                                        adj, mask8);
  k_pv<<<512, 512, 0, stream>>>(WhB, EA, EA2, EB, EB2, mask8, out);
}